// Round 8
// baseline (492.673 us; speedup 1.0000x reference)
//
#include <hip/hip_runtime.h>
#include <math.h>

#define NB   8
#define NC   256
#define ND   64
#define NPIX 4096
#define LSTR 72   // attn P LDS row stride (bf16 elems)

typedef short bf16x8 __attribute__((ext_vector_type(8)));   // 8 bf16 (4 VGPRs)
typedef float f32x4  __attribute__((ext_vector_type(4)));
typedef float f32x16 __attribute__((ext_vector_type(16)));

static __device__ __forceinline__ ushort f2bf(float f) {
    uint u = __float_as_uint(f);
    u += 0x7fffu + ((u >> 16) & 1u);      // round-to-nearest-even
    return (ushort)(u >> 16);
}
static __device__ __forceinline__ float bf2f(ushort h) {
    return __uint_as_float(((uint)h) << 16);
}

// ---------------------------------------------------------------------------
// transpose_x: x[b][c][p] f32 -> xt_h/xt_l [b][p][256] bf16 hi/lo.
// ---------------------------------------------------------------------------
__global__ __launch_bounds__(256) void transpose_x(
    const float* __restrict__ x, ushort* __restrict__ xth, ushort* __restrict__ xtl)
{
    __shared__ float tile[64][68];
    const int t = threadIdx.x;
    const int p0 = blockIdx.x * 64, c0 = blockIdx.y * 64, b = blockIdx.z;

    const int cl = t >> 4, p4 = (t & 15) * 4;
    #pragma unroll
    for (int i = 0; i < 4; i++) {
        const int c = cl + 16 * i;
        *(float4*)&tile[c][p4] =
            *(const float4*)&x[((size_t)(b * NC + c0 + c)) * NPIX + p0 + p4];
    }
    __syncthreads();

    const int pl = t & 63, ch = t >> 6;
    float v[16];
    #pragma unroll
    for (int j = 0; j < 16; j++) v[j] = tile[ch * 16 + j][pl];
    ushort h[16], l[16];
    #pragma unroll
    for (int j = 0; j < 16; j++) {
        h[j] = f2bf(v[j]);
        l[j] = f2bf(v[j] - bf2f(h[j]));
    }
    const size_t o = ((size_t)(b * NPIX + p0 + pl)) * 256 + c0 + ch * 16;
    *(uint4*)&xth[o]     = *(uint4*)&h[0];
    *(uint4*)&xth[o + 8] = *(uint4*)&h[8];
    *(uint4*)&xtl[o]     = *(uint4*)&l[0];
    *(uint4*)&xtl[o + 8] = *(uint4*)&l[8];
}

// ---------------------------------------------------------------------------
// transpose_w: W[co][ci][3][3] f32 -> wt[rs][co][ci] bf16 (hi/lo for q,k).
// ---------------------------------------------------------------------------
__global__ __launch_bounds__(256) void transpose_w(
    const float* __restrict__ Wq, const float* __restrict__ Wk,
    const float* __restrict__ Wv,
    ushort* __restrict__ qh, ushort* __restrict__ ql,
    ushort* __restrict__ kh, ushort* __restrict__ kl,
    ushort* __restrict__ vh)
{
    __shared__ float wb[2304];
    const int g = blockIdx.x, t = threadIdx.x;
    const float* src;
    ushort *dh, *dl;
    int co, Co, split;
    if (g < 64)       { src = Wq + (size_t)g * 2304; co = g;       Co = 64;  dh = qh; dl = ql; split = 1; }
    else if (g < 128) { src = Wk + (size_t)(g - 64) * 2304; co = g - 64; Co = 64; dh = kh; dl = kl; split = 1; }
    else              { src = Wv + (size_t)(g - 128) * 2304; co = g - 128; Co = 256; dh = vh; dl = nullptr; split = 0; }

    for (int i = t; i < 2304; i += 256) wb[i] = src[i];
    __syncthreads();
    for (int j = t; j < 2304; j += 256) {
        const int rs = j >> 8, ci = j & 255;
        const float v = wb[ci * 9 + rs];
        const ushort hv = f2bf(v);
        const size_t o = ((size_t)(rs * Co + co)) * 256 + ci;
        dh[o] = hv;
        if (split) dl[o] = f2bf(v - bf2f(hv));
    }
}

// ---------------------------------------------------------------------------
// conv_split body (R0-proven, bit-identical): split-bf16 3-term q/k conv.
// Block = 64co x 256pix (4 h-rows), wave=row. ci-chunk 16, padded to 24.
// Uses 65920 B of LDS.
// ---------------------------------------------------------------------------
static __device__ __forceinline__ void conv_split_body(
    char* smem, int hq, int b, int ct, int t,
    const ushort* __restrict__ xth, const ushort* __restrict__ xtl,
    const ushort* __restrict__ wqh, const ushort* __restrict__ wql,
    const ushort* __restrict__ wkh, const ushort* __restrict__ wkl,
    const float* __restrict__ bq, const float* __restrict__ bk,
    ushort* __restrict__ qoh, ushort* __restrict__ qol,
    ushort* __restrict__ koh, ushort* __restrict__ kol)
{
    ushort* xsh = (ushort*)smem;                 // [6][66][24]
    ushort* xsl = xsh + 6 * 66 * 24;             // [6][66][24]
    ushort* wsp = xsl + 6 * 66 * 24;             // [9][64][24] (one w-plane at a time)
    float*  sbias = (float*)(wsp + 9 * 64 * 24); // [64]

    const ushort* wth = ct ? wkh : wqh;
    const ushort* wtl = ct ? wkl : wql;
    const float*  bias = ct ? bk : bq;
    ushort* outh = ct ? koh : qoh;
    ushort* outl = ct ? kol : qol;

    const int wv = t >> 6, lane = t & 63;
    const int l31 = lane & 31, khl = lane >> 5;
    const int lanebase = l31 * 24 + khl * 8;
    const int h = hq * 4 + wv;

    if (t < 64) sbias[t] = bias[t];
    for (int i = t; i < 384; i += 256) {
        const int p = i / 192, r2 = i % 192;
        const int row = r2 / 32, e = (r2 % 32) / 16, ci = r2 & 15;
        (p ? xsl : xsh)[(row * 66 + e * 65) * 24 + ci] = 0;
    }

    f32x16 a00 = {0}, a01 = {0}, a10 = {0}, a11 = {0};  // [ms(co)][ns(pix)]

    for (int ch = 0; ch < 16; ch++) {
        __syncthreads();
        const int ci0 = ch * 16;
        #pragma unroll
        for (int pl2 = 0; pl2 < 2; pl2++) {
            const ushort* src = pl2 ? xtl : xth;
            ushort* dst = pl2 ? xsl : xsh;
            #pragma unroll
            for (int i = 0; i < 3; i++) {
                const int a = i * 256 + t;
                const int cih = a & 1, col = (a >> 1) & 63, row = a >> 7;
                const int hs = hq * 4 + row - 1;
                uint4 val = {0, 0, 0, 0};
                if (hs >= 0 && hs < 64)
                    val = *(const uint4*)&src[((size_t)(b * NPIX + hs * 64 + col)) * 256 + ci0 + cih * 8];
                *(uint4*)&dst[(row * 66 + 1 + col) * 24 + cih * 8] = val;
            }
        }
        #pragma unroll
        for (int i = 0; i < 5; i++) {
            const int a = i * 256 + t;
            if (a < 1152) {
                const int cih = a & 1, co = (a >> 1) & 63, rs = a >> 7;
                uint4 wv4 = *(const uint4*)&wth[((size_t)(rs * 64 + co)) * 256 + ci0 + cih * 8];
                *(uint4*)&wsp[(rs * 64 + co) * 24 + cih * 8] = wv4;
            }
        }
        __syncthreads();
        // pass0: (wh.xh) + (wh.xl)
        #pragma unroll
        for (int rs = 0; rs < 9; rs++) {
            const int r = rs / 3, s = rs % 3;
            bf16x8 A0 = *(const bf16x8*)&wsp[rs * 1536 + lanebase];
            bf16x8 A1 = *(const bf16x8*)&wsp[rs * 1536 + 768 + lanebase];
            const int xo = ((wv + r) * 66 + s) * 24 + lanebase;
            bf16x8 B0h = *(const bf16x8*)&xsh[xo];
            bf16x8 B1h = *(const bf16x8*)&xsh[xo + 768];
            bf16x8 B0l = *(const bf16x8*)&xsl[xo];
            bf16x8 B1l = *(const bf16x8*)&xsl[xo + 768];
            a00 = __builtin_amdgcn_mfma_f32_32x32x16_bf16(A0, B0h, a00, 0, 0, 0);
            a01 = __builtin_amdgcn_mfma_f32_32x32x16_bf16(A0, B1h, a01, 0, 0, 0);
            a10 = __builtin_amdgcn_mfma_f32_32x32x16_bf16(A1, B0h, a10, 0, 0, 0);
            a11 = __builtin_amdgcn_mfma_f32_32x32x16_bf16(A1, B1h, a11, 0, 0, 0);
            a00 = __builtin_amdgcn_mfma_f32_32x32x16_bf16(A0, B0l, a00, 0, 0, 0);
            a01 = __builtin_amdgcn_mfma_f32_32x32x16_bf16(A0, B1l, a01, 0, 0, 0);
            a10 = __builtin_amdgcn_mfma_f32_32x32x16_bf16(A1, B0l, a10, 0, 0, 0);
            a11 = __builtin_amdgcn_mfma_f32_32x32x16_bf16(A1, B1l, a11, 0, 0, 0);
        }
        __syncthreads();
        #pragma unroll
        for (int i = 0; i < 5; i++) {
            const int a = i * 256 + t;
            if (a < 1152) {
                const int cih = a & 1, co = (a >> 1) & 63, rs = a >> 7;
                uint4 wv4 = *(const uint4*)&wtl[((size_t)(rs * 64 + co)) * 256 + ci0 + cih * 8];
                *(uint4*)&wsp[(rs * 64 + co) * 24 + cih * 8] = wv4;
            }
        }
        __syncthreads();
        // pass1: (wl.xh)
        #pragma unroll
        for (int rs = 0; rs < 9; rs++) {
            const int r = rs / 3, s = rs % 3;
            bf16x8 A0 = *(const bf16x8*)&wsp[rs * 1536 + lanebase];
            bf16x8 A1 = *(const bf16x8*)&wsp[rs * 1536 + 768 + lanebase];
            const int xo = ((wv + r) * 66 + s) * 24 + lanebase;
            bf16x8 B0h = *(const bf16x8*)&xsh[xo];
            bf16x8 B1h = *(const bf16x8*)&xsh[xo + 768];
            a00 = __builtin_amdgcn_mfma_f32_32x32x16_bf16(A0, B0h, a00, 0, 0, 0);
            a01 = __builtin_amdgcn_mfma_f32_32x32x16_bf16(A0, B1h, a01, 0, 0, 0);
            a10 = __builtin_amdgcn_mfma_f32_32x32x16_bf16(A1, B0h, a10, 0, 0, 0);
            a11 = __builtin_amdgcn_mfma_f32_32x32x16_bf16(A1, B1h, a11, 0, 0, 0);
        }
    }

    const float4* sb4 = (const float4*)sbias;
    #pragma unroll
    for (int ms = 0; ms < 2; ms++)
        #pragma unroll
        for (int ns = 0; ns < 2; ns++) {
            const f32x16 av = ms ? (ns ? a11 : a10) : (ns ? a01 : a00);
            const int p = h * 64 + ns * 32 + l31;
            #pragma unroll
            for (int g = 0; g < 4; g++) {
                const float4 bi = sb4[ms * 8 + 2 * g + khl];
                float v0 = av[4 * g + 0] + bi.x;
                float v1 = av[4 * g + 1] + bi.y;
                float v2 = av[4 * g + 2] + bi.z;
                float v3 = av[4 * g + 3] + bi.w;
                ushort4 hv, lv;
                hv.x = f2bf(v0); lv.x = f2bf(v0 - bf2f(hv.x));
                hv.y = f2bf(v1); lv.y = f2bf(v1 - bf2f(hv.y));
                hv.z = f2bf(v2); lv.z = f2bf(v2 - bf2f(hv.z));
                hv.w = f2bf(v3); lv.w = f2bf(v3 - bf2f(hv.w));
                const size_t o = ((size_t)(b * NPIX + p)) * 64 + ms * 32 + 8 * g + 4 * khl;
                *(ushort4*)&outh[o] = hv;
                *(ushort4*)&outl[o] = lv;
            }
        }
}

// ---------------------------------------------------------------------------
// conv_v body (R0-proven, bit-identical): plain bf16 v conv.
// A = x (m=pixel), B = w (n=co). Uses 46912 B of LDS.
// ---------------------------------------------------------------------------
static __device__ __forceinline__ void conv_v_body(
    char* smem, int hq, int b, int co0, int t,
    const ushort* __restrict__ xth, const ushort* __restrict__ wtv,
    const float* __restrict__ bv, ushort* __restrict__ vout)
{
    ushort* xsh = (ushort*)smem;                 // [6][66][24]
    ushort* wsp = xsh + 6 * 66 * 24;             // [9][64][24]
    float*  sbias = (float*)(wsp + 9 * 64 * 24); // [64]

    const int wv = t >> 6, lane = t & 63;
    const int l31 = lane & 31, khl = lane >> 5;
    const int lanebase = l31 * 24 + khl * 8;
    const int h = hq * 4 + wv;

    if (t < 64) sbias[t] = bv[co0 + t];
    for (int i = t; i < 192; i += 256) {
        const int row = i / 32, e = (i % 32) / 16, ci = i & 15;
        xsh[(row * 66 + e * 65) * 24 + ci] = 0;
    }

    f32x16 a00 = {0}, a01 = {0}, a10 = {0}, a11 = {0};  // [ms(pix)][ns(co)]

    for (int ch = 0; ch < 16; ch++) {
        __syncthreads();
        const int ci0 = ch * 16;
        #pragma unroll
        for (int i = 0; i < 3; i++) {
            const int a = i * 256 + t;
            const int cih = a & 1, col = (a >> 1) & 63, row = a >> 7;
            const int hs = hq * 4 + row - 1;
            uint4 val = {0, 0, 0, 0};
            if (hs >= 0 && hs < 64)
                val = *(const uint4*)&xth[((size_t)(b * NPIX + hs * 64 + col)) * 256 + ci0 + cih * 8];
            *(uint4*)&xsh[(row * 66 + 1 + col) * 24 + cih * 8] = val;
        }
        #pragma unroll
        for (int i = 0; i < 5; i++) {
            const int a = i * 256 + t;
            if (a < 1152) {
                const int cih = a & 1, co = (a >> 1) & 63, rs = a >> 7;
                uint4 wv4 = *(const uint4*)&wtv[((size_t)(rs * 256 + co0 + co)) * 256 + ci0 + cih * 8];
                *(uint4*)&wsp[(rs * 64 + co) * 24 + cih * 8] = wv4;
            }
        }
        __syncthreads();
        #pragma unroll
        for (int rs = 0; rs < 9; rs++) {
            const int r = rs / 3, s = rs % 3;
            const int xo = ((wv + r) * 66 + s) * 24 + lanebase;
            bf16x8 A0 = *(const bf16x8*)&xsh[xo];
            bf16x8 A1 = *(const bf16x8*)&xsh[xo + 768];
            bf16x8 B0 = *(const bf16x8*)&wsp[rs * 1536 + lanebase];
            bf16x8 B1 = *(const bf16x8*)&wsp[rs * 1536 + 768 + lanebase];
            a00 = __builtin_amdgcn_mfma_f32_32x32x16_bf16(A0, B0, a00, 0, 0, 0);
            a01 = __builtin_amdgcn_mfma_f32_32x32x16_bf16(A0, B1, a01, 0, 0, 0);
            a10 = __builtin_amdgcn_mfma_f32_32x32x16_bf16(A1, B0, a10, 0, 0, 0);
            a11 = __builtin_amdgcn_mfma_f32_32x32x16_bf16(A1, B1, a11, 0, 0, 0);
        }
    }

    #pragma unroll
    for (int ns = 0; ns < 2; ns++) {
        const int co = co0 + ns * 32 + l31;
        const float bi = sbias[ns * 32 + l31];
        #pragma unroll
        for (int ms = 0; ms < 2; ms++) {
            const f32x16 av = ms ? (ns ? a11 : a10) : (ns ? a01 : a00);
            #pragma unroll
            for (int g = 0; g < 4; g++) {
                const int p = h * 64 + ms * 32 + 8 * g + 4 * khl;
                ushort4 ov;
                ov.x = f2bf(av[4 * g + 0] + bi);
                ov.y = f2bf(av[4 * g + 1] + bi);
                ov.z = f2bf(av[4 * g + 2] + bi);
                ov.w = f2bf(av[4 * g + 3] + bi);
                *(ushort4*)&vout[((size_t)(b * NC + co)) * NPIX + p] = ov;
            }
        }
    }
}

// ---------------------------------------------------------------------------
// FUSED conv launch, 768 blocks, INTERLEAVED type mapping (R7 fix):
//   gid % 3 == 0 -> conv_split (sid = gid/3, 256 blocks)
//   else         -> conv_v     (vid = gid - gid/3 - 1, 512 blocks)
// R7 mapped types in contiguous id ranges; in-order dispatch at 2 blocks/CU
// packed split-blocks pairwise on half the CUs (homogeneous co-residency =
// R5's proven null) and never mixed types. Interleaving puts one split-block
// + one v-block on (nearly) every CU: heterogeneous phase structures fill
// each other's stage/barrier stalls. dyn LDS 65920 B -> 2 blocks/CU.
// ---------------------------------------------------------------------------
__global__ __launch_bounds__(256) void conv_fused_k(
    const ushort* __restrict__ xth, const ushort* __restrict__ xtl,
    const ushort* __restrict__ wqh, const ushort* __restrict__ wql,
    const ushort* __restrict__ wkh, const ushort* __restrict__ wkl,
    const ushort* __restrict__ wtv,
    const float* __restrict__ bq, const float* __restrict__ bk,
    const float* __restrict__ bv,
    ushort* __restrict__ qoh, ushort* __restrict__ qol,
    ushort* __restrict__ koh, ushort* __restrict__ kol,
    ushort* __restrict__ vout)
{
    extern __shared__ char smem[];
    const int gid = blockIdx.x;
    const int t = threadIdx.x;
    const int d3 = gid / 3;
    if (gid - d3 * 3 == 0) {
        const int sid = d3;                       // 0..255
        conv_split_body(smem, sid & 15, (sid >> 4) & 7, sid >> 7, t,
                        xth, xtl, wqh, wql, wkh, wkl, bq, bk,
                        qoh, qol, koh, kol);
    } else {
        const int vid = gid - d3 - 1;             // 0..511
        conv_v_body(smem, vid & 15, (vid >> 4) & 7, (vid >> 7) * 64, t,
                    xth, wtv, bv, vout);
    }
}

// ---------------------------------------------------------------------------
// MFMA flash attention v6 (R2-proven session best): m-tile 64, 2 blocks/CU,
// ONE non-draining barrier per iter (lgkmcnt only -> K/V register prefetches
// stay in flight), setprio(1) around PV MFMA cluster.
// grid 512 1-D (b = id&7 -> XCD pin), block 256, LDS ~20 KB.
// ---------------------------------------------------------------------------
__global__ __launch_bounds__(256, 2) void attn_k(
    const ushort* __restrict__ qh, const ushort* __restrict__ ql,
    const ushort* __restrict__ kh, const ushort* __restrict__ kl,
    const ushort* __restrict__ vb, const float* __restrict__ x,
    float* __restrict__ out)
{
    const int id = blockIdx.x;
    const int b  = id & 7;
    const int m0 = (id >> 3) * 64;
    const int t  = threadIdx.x;
    const int w  = t >> 6;
    const int lane = t & 63;
    const int quad = lane >> 4;
    const int l16  = lane & 15;

    __shared__ ushort sps[2][64 * LSTR];   // P double buffer
    __shared__ float  red[4][64];
    __shared__ float  ivl[64];

    // hoisted Q B-frags: B[col=m=l16][k=d]
    bf16x8 aqh[4][2], aql[4][2];
    #pragma unroll
    for (int mg = 0; mg < 4; mg++)
        #pragma unroll
        for (int ks = 0; ks < 2; ks++) {
            const size_t g = ((size_t)b * NPIX + m0 + mg * 16 + l16) * ND + ks * 32 + quad * 8;
            aqh[mg][ks] = *(const bf16x8*)&qh[g];
            aql[mg][ks] = *(const bf16x8*)&ql[g];
        }

    // per-wave base offsets
    const size_t kbase = ((size_t)b * NPIX + 16 * w + l16) * ND + quad * 8;   // + n0*ND + ks*32
    size_t vbase[4];
    #pragma unroll
    for (int ct = 0; ct < 4; ct++)
        vbase[ct] = ((size_t)b * NC + 64 * w + ct * 16 + l16) * NPIX + quad * 8;  // + n0 + ks*32

    // preload K/V frags for n0 = 0
    bf16x8 kfh[2], kfl[2], vf[4][2];
    #pragma unroll
    for (int ks = 0; ks < 2; ks++) {
        kfh[ks] = *(const bf16x8*)&kh[kbase + ks * 32];
        kfl[ks] = *(const bf16x8*)&kl[kbase + ks * 32];
    }
    #pragma unroll
    for (int ct = 0; ct < 4; ct++)
        #pragma unroll
        for (int ks = 0; ks < 2; ks++)
            vf[ct][ks] = *(const bf16x8*)&vb[vbase[ct] + ks * 32];

    f32x4 acc[4][4];
    #pragma unroll
    for (int i = 0; i < 4; i++)
        #pragma unroll
        for (int j = 0; j < 4; j++) acc[i][j] = (f32x4){0.f, 0.f, 0.f, 0.f};
    float lsum[4] = {0.f, 0.f, 0.f, 0.f};

    for (int n0 = 0; n0 < NPIX; n0 += 64) {
        const int buf = (n0 >> 6) & 1;
        const bool nxt = (n0 + 64) < NPIX;

        // ---- QK (S^T = K.Q^T), exp, pack -> sps[buf] ----
        #pragma unroll
        for (int mg = 0; mg < 4; mg++) {
            f32x4 s = {0.f, 0.f, 0.f, 0.f};
            #pragma unroll
            for (int ks = 0; ks < 2; ks++) {
                s = __builtin_amdgcn_mfma_f32_16x16x32_bf16(kfh[ks], aqh[mg][ks], s, 0, 0, 0);
                s = __builtin_amdgcn_mfma_f32_16x16x32_bf16(kfl[ks], aqh[mg][ks], s, 0, 0, 0);
                s = __builtin_amdgcn_mfma_f32_16x16x32_bf16(kfh[ks], aql[mg][ks], s, 0, 0, 0);
            }
            uint2 pk;
            {
                const ushort p0 = f2bf(__expf(s[0] - 30.f));
                const ushort p1 = f2bf(__expf(s[1] - 30.f));
                const ushort p2 = f2bf(__expf(s[2] - 30.f));
                const ushort p3 = f2bf(__expf(s[3] - 30.f));
                lsum[mg] += (bf2f(p0) + bf2f(p1)) + (bf2f(p2) + bf2f(p3));
                pk.x = (uint)p0 | ((uint)p1 << 16);
                pk.y = (uint)p2 | ((uint)p3 << 16);
            }
            *(uint2*)&sps[buf][(mg * 16 + l16) * LSTR + 16 * w + quad * 4] = pk;
        }

        // K prefetch for n0+64 (kf dead after QK; stays in flight across the
        // non-draining barrier, lands under PV)
        if (nxt) {
            const size_t kb = kbase + (size_t)(n0 + 64) * ND;
            #pragma unroll
            for (int ks = 0; ks < 2; ks++) {
                kfh[ks] = *(const bf16x8*)&kh[kb + ks * 32];
                kfl[ks] = *(const bf16x8*)&kl[kb + ks * 32];
            }
        }

        // non-draining barrier: LDS writes visible (lgkmcnt(0)), global
        // prefetches NOT drained (no vmcnt(0) — unlike __syncthreads()).
        asm volatile("s_waitcnt lgkmcnt(0)\n\ts_barrier" ::: "memory");

        // ---- PV: A = P frags (LDS), B = V frags (regs) ----
        __builtin_amdgcn_s_setprio(1);
        #pragma unroll
        for (int ks = 0; ks < 2; ks++) {
            bf16x8 ap[4];
            #pragma unroll
            for (int mg = 0; mg < 4; mg++)
                ap[mg] = *(const bf16x8*)&sps[buf][(mg * 16 + l16) * LSTR + ks * 32 + quad * 8];
            #pragma unroll
            for (int mg = 0; mg < 4; mg++)
                #pragma unroll
                for (int ct = 0; ct < 4; ct++)
                    acc[mg][ct] = __builtin_amdgcn_mfma_f32_16x16x32_bf16(
                        ap[mg], vf[ct][ks], acc[mg][ct], 0, 0, 0);
        }
        __builtin_amdgcn_s_setprio(0);

        // V prefetch for n0+64 (vf dead after PV; lands during next QK+exp)
        if (nxt) {
            #pragma unroll
            for (int ct = 0; ct < 4; ct++)
                #pragma unroll
                for (int ks = 0; ks < 2; ks++)
                    vf[ct][ks] = *(const bf16x8*)&vb[vbase[ct] + n0 + 64 + ks * 32];
        }
    }

    // rowsum: reduce across quad lanes, then across the 4 nt-waves via LDS
    #pragma unroll
    for (int mg = 0; mg < 4; mg++) {
        lsum[mg] += __shfl_xor(lsum[mg], 16, 64);
        lsum[mg] += __shfl_xor(lsum[mg], 32, 64);
    }
    if (quad == 0) {
        #pragma unroll
        for (int mg = 0; mg < 4; mg++) red[w][mg * 16 + l16] = lsum[mg];
    }
    __syncthreads();
    if (t < 64)
        ivl[t] = 1.f / (red[0][t] + red[1][t] + red[2][t] + red[3][t]);
    __syncthreads();

    // epilogue: out = acc/l + x; D rows m = mg*16+quad*4+r, col c = l16
    #pragma unroll
    for (int mg = 0; mg < 4; mg++) {
        const int mrow = mg * 16 + quad * 4;
        const float4 il4 = *(const float4*)&ivl[mrow];
        const int m = m0 + mrow;
        #pragma unroll
        for (int ct = 0; ct < 4; ct++) {
            const int c = 64 * w + ct * 16 + l16;
            const size_t base = ((size_t)b * NC + c) * NPIX + m;
            const float4 xv = *(const float4*)&x[base];
            const f32x4 a = acc[mg][ct];
            float4 o;
            o.x = fmaf(a[0], il4.x, xv.x);
            o.y = fmaf(a[1], il4.y, xv.y);
            o.z = fmaf(a[2], il4.z, xv.z);
            o.w = fmaf(a[3], il4.w, xv.w);
            *(float4*)&out[base] = o;
        }
    }
}

extern "C" void kernel_launch(void* const* d_in, const int* in_sizes, int n_in,
                              void* d_out, int out_size, void* d_ws, size_t ws_size,
                              hipStream_t stream)
{
    const float* x  = (const float*)d_in[0];
    const float* Wq = (const float*)d_in[1];
    const float* bq = (const float*)d_in[2];
    const float* Wk = (const float*)d_in[3];
    const float* bk = (const float*)d_in[4];
    const float* Wv = (const float*)d_in[5];
    const float* bv = (const float*)d_in[6];
    float* outp = (float*)d_out;

    const size_t XT = (size_t)NB * NPIX * 256;   // 8,388,608
    const size_t QK = (size_t)NB * NPIX * ND;    // 2,097,152
    ushort* xt_h = (ushort*)d_ws;
    ushort* xt_l = xt_h + XT;
    ushort* q_h  = xt_l + XT;
    ushort* q_l  = q_h + QK;
    ushort* k_h  = q_l + QK;
    ushort* k_l  = k_h + QK;
    ushort* wtq_h = k_l + QK;         // 9*64*256 = 147456 each
    ushort* wtq_l = wtq_h + 147456;
    ushort* wtk_h = wtq_l + 147456;
    ushort* wtk_l = wtk_h + 147456;
    ushort* wtv_h = wtk_l + 147456;   // 9*256*256 = 589824
    ushort* v_b   = wtv_h + 589824;   // DEDICATED buffer (no xt_l alias) so
                                      // conv_split & conv_v can run fused.
                                      // Total ws: ~69.5 MB (validated in R7).

    dim3 blk(256);
    transpose_x<<<dim3(64, 4, NB), blk, 0, stream>>>(x, xt_h, xt_l);
    transpose_w<<<dim3(384), blk, 0, stream>>>(Wq, Wk, Wv, wtq_h, wtq_l, wtk_h, wtk_l, wtv_h);
    conv_fused_k<<<dim3(768), blk, 65920, stream>>>(
        xt_h, xt_l, wtq_h, wtq_l, wtk_h, wtk_l, wtv_h, bq, bk, bv,
        q_h, q_l, k_h, k_l, v_b);
    attn_k<<<dim3(512), blk, 0, stream>>>(q_h, q_l, k_h, k_l, v_b, x, outp);
}

// Round 9
// 421.338 us; speedup vs baseline: 1.1693x; 1.1693x over previous
//
#include <hip/hip_runtime.h>
#include <math.h>

#define NB   8
#define NC   256
#define ND   64
#define NPIX 4096

typedef short bf16x8 __attribute__((ext_vector_type(8)));   // 8 bf16 (4 VGPRs)
typedef float f32x4  __attribute__((ext_vector_type(4)));
typedef float f32x16 __attribute__((ext_vector_type(16)));

static __device__ __forceinline__ ushort f2bf(float f) {
    uint u = __float_as_uint(f);
    u += 0x7fffu + ((u >> 16) & 1u);      // round-to-nearest-even
    return (ushort)(u >> 16);
}
static __device__ __forceinline__ float bf2f(ushort h) {
    return __uint_as_float(((uint)h) << 16);
}

// ---------------------------------------------------------------------------
// prep_k: transpose_w (ids 0..383) + transpose_x (ids 384..2431) fused into
// ONE dispatch. Bodies verbatim from the proven serial kernels; both are
// single-pass streaming (no L2 locality to lose — unlike the conv fusion,
// R7/R8). w-blocks first so they overlap fully under transpose_x.
// Shared LDS buffer: max(64*68*4, 2304*4) = 17408 B.
// ---------------------------------------------------------------------------
__global__ __launch_bounds__(256) void prep_k(
    const float* __restrict__ x,
    const float* __restrict__ Wq, const float* __restrict__ Wk,
    const float* __restrict__ Wv,
    ushort* __restrict__ xth, ushort* __restrict__ xtl,
    ushort* __restrict__ qh, ushort* __restrict__ ql,
    ushort* __restrict__ kh, ushort* __restrict__ kl,
    ushort* __restrict__ vh)
{
    __shared__ char shbuf[64 * 68 * 4];
    const int id = blockIdx.x;
    const int t = threadIdx.x;

    if (id < 384) {
        // ---- transpose_w body (g = id) ----
        float* wb = (float*)shbuf;
        const int g = id;
        const float* src;
        ushort *dh, *dl;
        int co, Co, split;
        if (g < 64)       { src = Wq + (size_t)g * 2304; co = g;       Co = 64;  dh = qh; dl = ql; split = 1; }
        else if (g < 128) { src = Wk + (size_t)(g - 64) * 2304; co = g - 64; Co = 64; dh = kh; dl = kl; split = 1; }
        else              { src = Wv + (size_t)(g - 128) * 2304; co = g - 128; Co = 256; dh = vh; dl = nullptr; split = 0; }

        for (int i = t; i < 2304; i += 256) wb[i] = src[i];
        __syncthreads();
        for (int j = t; j < 2304; j += 256) {
            const int rs = j >> 8, ci = j & 255;
            const float v = wb[ci * 9 + rs];
            const ushort hv = f2bf(v);
            const size_t o = ((size_t)(rs * Co + co)) * 256 + ci;
            dh[o] = hv;
            if (split) dl[o] = f2bf(v - bf2f(hv));
        }
    } else {
        // ---- transpose_x body (xid = id - 384) ----
        float (*tile)[68] = (float(*)[68])shbuf;
        const int xid = id - 384;
        const int p0 = (xid & 63) * 64, c0 = ((xid >> 6) & 3) * 64, b = xid >> 8;

        const int cl = t >> 4, p4 = (t & 15) * 4;
        #pragma unroll
        for (int i = 0; i < 4; i++) {
            const int c = cl + 16 * i;
            *(float4*)&tile[c][p4] =
                *(const float4*)&x[((size_t)(b * NC + c0 + c)) * NPIX + p0 + p4];
        }
        __syncthreads();

        const int pl = t & 63, ch = t >> 6;
        float v[16];
        #pragma unroll
        for (int j = 0; j < 16; j++) v[j] = tile[ch * 16 + j][pl];
        ushort h[16], l[16];
        #pragma unroll
        for (int j = 0; j < 16; j++) {
            h[j] = f2bf(v[j]);
            l[j] = f2bf(v[j] - bf2f(h[j]));
        }
        const size_t o = ((size_t)(b * NPIX + p0 + pl)) * 256 + c0 + ch * 16;
        *(uint4*)&xth[o]     = *(uint4*)&h[0];
        *(uint4*)&xth[o + 8] = *(uint4*)&h[8];
        *(uint4*)&xtl[o]     = *(uint4*)&l[0];
        *(uint4*)&xtl[o + 8] = *(uint4*)&l[8];
    }
}

// ---------------------------------------------------------------------------
// MFMA conv (q/k, split-bf16 3-term). R0 structure (proven, no spills).
// Block = 64co x 256pix (4 rows), wave=row. ci-chunk 16, ci padded to 24.
// grid (16 hq, 8 b, 2 {q,k}), dyn LDS 65920 B.
// ---------------------------------------------------------------------------
__global__ __launch_bounds__(256) void conv_split_k(
    const ushort* __restrict__ xth, const ushort* __restrict__ xtl,
    const ushort* __restrict__ wqh, const ushort* __restrict__ wql,
    const ushort* __restrict__ wkh, const ushort* __restrict__ wkl,
    const float* __restrict__ bq, const float* __restrict__ bk,
    ushort* __restrict__ qoh, ushort* __restrict__ qol,
    ushort* __restrict__ koh, ushort* __restrict__ kol)
{
    extern __shared__ char smem[];
    ushort* xsh = (ushort*)smem;                 // [6][66][24]
    ushort* xsl = xsh + 6 * 66 * 24;             // [6][66][24]
    ushort* wsp = xsl + 6 * 66 * 24;             // [9][64][24] (one w-plane at a time)
    float*  sbias = (float*)(wsp + 9 * 64 * 24); // [64]

    const int hq = blockIdx.x, b = blockIdx.y, ct = blockIdx.z;
    const ushort* wth = ct ? wkh : wqh;
    const ushort* wtl = ct ? wkl : wql;
    const float*  bias = ct ? bk : bq;
    ushort* outh = ct ? koh : qoh;
    ushort* outl = ct ? kol : qol;

    const int t = threadIdx.x;
    const int wv = t >> 6, lane = t & 63;
    const int l31 = lane & 31, khl = lane >> 5;
    const int lanebase = l31 * 24 + khl * 8;
    const int h = hq * 4 + wv;

    if (t < 64) sbias[t] = bias[t];
    for (int i = t; i < 384; i += 256) {
        const int p = i / 192, r2 = i % 192;
        const int row = r2 / 32, e = (r2 % 32) / 16, ci = r2 & 15;
        (p ? xsl : xsh)[(row * 66 + e * 65) * 24 + ci] = 0;
    }

    f32x16 a00 = {0}, a01 = {0}, a10 = {0}, a11 = {0};  // [ms(co)][ns(pix)]

    for (int ch = 0; ch < 16; ch++) {
        __syncthreads();
        const int ci0 = ch * 16;
        #pragma unroll
        for (int pl2 = 0; pl2 < 2; pl2++) {
            const ushort* src = pl2 ? xtl : xth;
            ushort* dst = pl2 ? xsl : xsh;
            #pragma unroll
            for (int i = 0; i < 3; i++) {
                const int a = i * 256 + t;
                const int cih = a & 1, col = (a >> 1) & 63, row = a >> 7;
                const int hs = hq * 4 + row - 1;
                uint4 val = {0, 0, 0, 0};
                if (hs >= 0 && hs < 64)
                    val = *(const uint4*)&src[((size_t)(b * NPIX + hs * 64 + col)) * 256 + ci0 + cih * 8];
                *(uint4*)&dst[(row * 66 + 1 + col) * 24 + cih * 8] = val;
            }
        }
        #pragma unroll
        for (int i = 0; i < 5; i++) {
            const int a = i * 256 + t;
            if (a < 1152) {
                const int cih = a & 1, co = (a >> 1) & 63, rs = a >> 7;
                uint4 wv4 = *(const uint4*)&wth[((size_t)(rs * 64 + co)) * 256 + ci0 + cih * 8];
                *(uint4*)&wsp[(rs * 64 + co) * 24 + cih * 8] = wv4;
            }
        }
        __syncthreads();
        // pass0: (wh.xh) + (wh.xl)
        #pragma unroll
        for (int rs = 0; rs < 9; rs++) {
            const int r = rs / 3, s = rs % 3;
            bf16x8 A0 = *(const bf16x8*)&wsp[rs * 1536 + lanebase];
            bf16x8 A1 = *(const bf16x8*)&wsp[rs * 1536 + 768 + lanebase];
            const int xo = ((wv + r) * 66 + s) * 24 + lanebase;
            bf16x8 B0h = *(const bf16x8*)&xsh[xo];
            bf16x8 B1h = *(const bf16x8*)&xsh[xo + 768];
            bf16x8 B0l = *(const bf16x8*)&xsl[xo];
            bf16x8 B1l = *(const bf16x8*)&xsl[xo + 768];
            a00 = __builtin_amdgcn_mfma_f32_32x32x16_bf16(A0, B0h, a00, 0, 0, 0);
            a01 = __builtin_amdgcn_mfma_f32_32x32x16_bf16(A0, B1h, a01, 0, 0, 0);
            a10 = __builtin_amdgcn_mfma_f32_32x32x16_bf16(A1, B0h, a10, 0, 0, 0);
            a11 = __builtin_amdgcn_mfma_f32_32x32x16_bf16(A1, B1h, a11, 0, 0, 0);
            a00 = __builtin_amdgcn_mfma_f32_32x32x16_bf16(A0, B0l, a00, 0, 0, 0);
            a01 = __builtin_amdgcn_mfma_f32_32x32x16_bf16(A0, B1l, a01, 0, 0, 0);
            a10 = __builtin_amdgcn_mfma_f32_32x32x16_bf16(A1, B0l, a10, 0, 0, 0);
            a11 = __builtin_amdgcn_mfma_f32_32x32x16_bf16(A1, B1l, a11, 0, 0, 0);
        }
        __syncthreads();
        #pragma unroll
        for (int i = 0; i < 5; i++) {
            const int a = i * 256 + t;
            if (a < 1152) {
                const int cih = a & 1, co = (a >> 1) & 63, rs = a >> 7;
                uint4 wv4 = *(const uint4*)&wtl[((size_t)(rs * 64 + co)) * 256 + ci0 + cih * 8];
                *(uint4*)&wsp[(rs * 64 + co) * 24 + cih * 8] = wv4;
            }
        }
        __syncthreads();
        // pass1: (wl.xh)
        #pragma unroll
        for (int rs = 0; rs < 9; rs++) {
            const int r = rs / 3, s = rs % 3;
            bf16x8 A0 = *(const bf16x8*)&wsp[rs * 1536 + lanebase];
            bf16x8 A1 = *(const bf16x8*)&wsp[rs * 1536 + 768 + lanebase];
            const int xo = ((wv + r) * 66 + s) * 24 + lanebase;
            bf16x8 B0h = *(const bf16x8*)&xsh[xo];
            bf16x8 B1h = *(const bf16x8*)&xsh[xo + 768];
            a00 = __builtin_amdgcn_mfma_f32_32x32x16_bf16(A0, B0h, a00, 0, 0, 0);
            a01 = __builtin_amdgcn_mfma_f32_32x32x16_bf16(A0, B1h, a01, 0, 0, 0);
            a10 = __builtin_amdgcn_mfma_f32_32x32x16_bf16(A1, B0h, a10, 0, 0, 0);
            a11 = __builtin_amdgcn_mfma_f32_32x32x16_bf16(A1, B1h, a11, 0, 0, 0);
        }
    }

    const float4* sb4 = (const float4*)sbias;
    #pragma unroll
    for (int ms = 0; ms < 2; ms++)
        #pragma unroll
        for (int ns = 0; ns < 2; ns++) {
            const f32x16 av = ms ? (ns ? a11 : a10) : (ns ? a01 : a00);
            const int p = h * 64 + ns * 32 + l31;
            #pragma unroll
            for (int g = 0; g < 4; g++) {
                const float4 bi = sb4[ms * 8 + 2 * g + khl];
                float v0 = av[4 * g + 0] + bi.x;
                float v1 = av[4 * g + 1] + bi.y;
                float v2 = av[4 * g + 2] + bi.z;
                float v3 = av[4 * g + 3] + bi.w;
                ushort4 hv, lv;
                hv.x = f2bf(v0); lv.x = f2bf(v0 - bf2f(hv.x));
                hv.y = f2bf(v1); lv.y = f2bf(v1 - bf2f(hv.y));
                hv.z = f2bf(v2); lv.z = f2bf(v2 - bf2f(hv.z));
                hv.w = f2bf(v3); lv.w = f2bf(v3 - bf2f(hv.w));
                const size_t o = ((size_t)(b * NPIX + p)) * 64 + ms * 32 + 8 * g + 4 * khl;
                *(ushort4*)&outh[o] = hv;
                *(ushort4*)&outl[o] = lv;
            }
        }
}

// ---------------------------------------------------------------------------
// MFMA conv (v, plain bf16). R0 structure. A = x (m=pixel), B = w (n=co).
// grid (16 hq, 8 b, 4 cotile), dyn LDS 46912 B.
// ---------------------------------------------------------------------------
__global__ __launch_bounds__(256) void conv_v_k(
    const ushort* __restrict__ xth, const ushort* __restrict__ wtv,
    const float* __restrict__ bv, ushort* __restrict__ vout)
{
    extern __shared__ char smem[];
    ushort* xsh = (ushort*)smem;                 // [6][66][24]
    ushort* wsp = xsh + 6 * 66 * 24;             // [9][64][24]
    float*  sbias = (float*)(wsp + 9 * 64 * 24); // [64]

    const int hq = blockIdx.x, b = blockIdx.y, co0 = blockIdx.z * 64;
    const int t = threadIdx.x;
    const int wv = t >> 6, lane = t & 63;
    const int l31 = lane & 31, khl = lane >> 5;
    const int lanebase = l31 * 24 + khl * 8;
    const int h = hq * 4 + wv;

    if (t < 64) sbias[t] = bv[co0 + t];
    for (int i = t; i < 192; i += 256) {
        const int row = i / 32, e = (i % 32) / 16, ci = i & 15;
        xsh[(row * 66 + e * 65) * 24 + ci] = 0;
    }

    f32x16 a00 = {0}, a01 = {0}, a10 = {0}, a11 = {0};  // [ms(pix)][ns(co)]

    for (int ch = 0; ch < 16; ch++) {
        __syncthreads();
        const int ci0 = ch * 16;
        #pragma unroll
        for (int i = 0; i < 3; i++) {
            const int a = i * 256 + t;
            const int cih = a & 1, col = (a >> 1) & 63, row = a >> 7;
            const int hs = hq * 4 + row - 1;
            uint4 val = {0, 0, 0, 0};
            if (hs >= 0 && hs < 64)
                val = *(const uint4*)&xth[((size_t)(b * NPIX + hs * 64 + col)) * 256 + ci0 + cih * 8];
            *(uint4*)&xsh[(row * 66 + 1 + col) * 24 + cih * 8] = val;
        }
        #pragma unroll
        for (int i = 0; i < 5; i++) {
            const int a = i * 256 + t;
            if (a < 1152) {
                const int cih = a & 1, co = (a >> 1) & 63, rs = a >> 7;
                uint4 wv4 = *(const uint4*)&wtv[((size_t)(rs * 256 + co0 + co)) * 256 + ci0 + cih * 8];
                *(uint4*)&wsp[(rs * 64 + co) * 24 + cih * 8] = wv4;
            }
        }
        __syncthreads();
        #pragma unroll
        for (int rs = 0; rs < 9; rs++) {
            const int r = rs / 3, s = rs % 3;
            const int xo = ((wv + r) * 66 + s) * 24 + lanebase;
            bf16x8 A0 = *(const bf16x8*)&xsh[xo];
            bf16x8 A1 = *(const bf16x8*)&xsh[xo + 768];
            bf16x8 B0 = *(const bf16x8*)&wsp[rs * 1536 + lanebase];
            bf16x8 B1 = *(const bf16x8*)&wsp[rs * 1536 + 768 + lanebase];
            a00 = __builtin_amdgcn_mfma_f32_32x32x16_bf16(A0, B0, a00, 0, 0, 0);
            a01 = __builtin_amdgcn_mfma_f32_32x32x16_bf16(A0, B1, a01, 0, 0, 0);
            a10 = __builtin_amdgcn_mfma_f32_32x32x16_bf16(A1, B0, a10, 0, 0, 0);
            a11 = __builtin_amdgcn_mfma_f32_32x32x16_bf16(A1, B1, a11, 0, 0, 0);
        }
    }

    #pragma unroll
    for (int ns = 0; ns < 2; ns++) {
        const int co = co0 + ns * 32 + l31;
        const float bi = sbias[ns * 32 + l31];
        #pragma unroll
        for (int ms = 0; ms < 2; ms++) {
            const f32x16 av = ms ? (ns ? a11 : a10) : (ns ? a01 : a00);
            #pragma unroll
            for (int g = 0; g < 4; g++) {
                const int p = h * 64 + ms * 32 + 8 * g + 4 * khl;
                ushort4 ov;
                ov.x = f2bf(av[4 * g + 0] + bi);
                ov.y = f2bf(av[4 * g + 1] + bi);
                ov.z = f2bf(av[4 * g + 2] + bi);
                ov.w = f2bf(av[4 * g + 3] + bi);
                *(ushort4*)&vout[((size_t)(b * NC + co)) * NPIX + p] = ov;
            }
        }
    }
}

// ---------------------------------------------------------------------------
// MFMA flash attention v7 (R3, session best 424.03us): pipeline-skewed.
// Each barrier interval: [issue swizzled P-reads for PV(n)] + [QK(n+64): 24
// reg-only MFMAs + exp + swizzled P-writes -> other buffer] + [PV(n): 32
// MFMAs]. ONE lgkm-only barrier per iter (K/V prefetches stay in flight).
// P buffer: 128B rows + XOR swizzle byte^=(row&7)<<4 both sides (bank-
// conflict 6.29M -> 2.10M, proven R3). Bit-identical numerics to v4.
// grid 512 1-D (b = id&7 -> XCD pin), block 256, LDS ~17.7 KB.
// ---------------------------------------------------------------------------
__global__ __launch_bounds__(256, 2) void attn_k(
    const ushort* __restrict__ qh, const ushort* __restrict__ ql,
    const ushort* __restrict__ kh, const ushort* __restrict__ kl,
    const ushort* __restrict__ vb, const float* __restrict__ x,
    float* __restrict__ out)
{
    const int id = blockIdx.x;
    const int b  = id & 7;
    const int m0 = (id >> 3) * 64;
    const int t  = threadIdx.x;
    const int w  = t >> 6;
    const int lane = t & 63;
    const int quad = lane >> 4;
    const int l16  = lane & 15;

    __shared__ ushort sps[2][64 * 64];   // P double buffer, 128B rows, swizzled
    __shared__ float  red[4][64];
    __shared__ float  ivl[64];

    // hoisted Q B-frags: B[col=m=l16][k=d]
    bf16x8 aqh[4][2], aql[4][2];
    #pragma unroll
    for (int mg = 0; mg < 4; mg++)
        #pragma unroll
        for (int ks = 0; ks < 2; ks++) {
            const size_t g = ((size_t)b * NPIX + m0 + mg * 16 + l16) * ND + ks * 32 + quad * 8;
            aqh[mg][ks] = *(const bf16x8*)&qh[g];
            aql[mg][ks] = *(const bf16x8*)&ql[g];
        }

    // per-wave base offsets
    const size_t kbase = ((size_t)b * NPIX + 16 * w + l16) * ND + quad * 8;   // + n0*ND + ks*32
    size_t vbase[4];
    #pragma unroll
    for (int ct = 0; ct < 4; ct++)
        vbase[ct] = ((size_t)b * NC + 64 * w + ct * 16 + l16) * NPIX + quad * 8;  // + n0 + ks*32

    // preload K/V frags for n0 = 0
    bf16x8 kfh[2], kfl[2], vf[4][2];
    #pragma unroll
    for (int ks = 0; ks < 2; ks++) {
        kfh[ks] = *(const bf16x8*)&kh[kbase + ks * 32];
        kfl[ks] = *(const bf16x8*)&kl[kbase + ks * 32];
    }
    #pragma unroll
    for (int ct = 0; ct < 4; ct++)
        #pragma unroll
        for (int ks = 0; ks < 2; ks++)
            vf[ct][ks] = *(const bf16x8*)&vb[vbase[ct] + ks * 32];

    f32x4 acc[4][4];
    #pragma unroll
    for (int i = 0; i < 4; i++)
        #pragma unroll
        for (int j = 0; j < 4; j++) acc[i][j] = (f32x4){0.f, 0.f, 0.f, 0.f};
    float lsum[4] = {0.f, 0.f, 0.f, 0.f};

    // QK tile: S^T = K.Q^T (kf regs hold this tile's K), exp, pack -> sps[obuf]
    auto qk_tile = [&](int obuf) {
        #pragma unroll
        for (int mg = 0; mg < 4; mg++) {
            f32x4 s = {0.f, 0.f, 0.f, 0.f};
            #pragma unroll
            for (int ks = 0; ks < 2; ks++) {
                s = __builtin_amdgcn_mfma_f32_16x16x32_bf16(kfh[ks], aqh[mg][ks], s, 0, 0, 0);
                s = __builtin_amdgcn_mfma_f32_16x16x32_bf16(kfl[ks], aqh[mg][ks], s, 0, 0, 0);
                s = __builtin_amdgcn_mfma_f32_16x16x32_bf16(kfh[ks], aql[mg][ks], s, 0, 0, 0);
            }
            const ushort p0 = f2bf(__expf(s[0] - 30.f));
            const ushort p1 = f2bf(__expf(s[1] - 30.f));
            const ushort p2 = f2bf(__expf(s[2] - 30.f));
            const ushort p3 = f2bf(__expf(s[3] - 30.f));
            lsum[mg] += (bf2f(p0) + bf2f(p1)) + (bf2f(p2) + bf2f(p3));
            uint2 pk;
            pk.x = (uint)p0 | ((uint)p1 << 16);
            pk.y = (uint)p2 | ((uint)p3 << 16);
            const int row = mg * 16 + l16;
            const int bo = (32 * w + quad * 8) ^ ((row & 7) << 4);
            *(uint2*)((char*)&sps[obuf][0] + row * 128 + bo) = pk;
        }
    };

    // prologue: QK(0) -> sps[0]; prefetch K(64); barrier
    qk_tile(0);
    {
        const size_t kb = kbase + (size_t)64 * ND;
        #pragma unroll
        for (int ks = 0; ks < 2; ks++) {
            kfh[ks] = *(const bf16x8*)&kh[kb + ks * 32];
            kfl[ks] = *(const bf16x8*)&kl[kb + ks * 32];
        }
    }
    asm volatile("s_waitcnt lgkmcnt(0)\n\ts_barrier" ::: "memory");

    for (int n0 = 0; n0 < NPIX; n0 += 64) {
        const int buf = (n0 >> 6) & 1;
        const bool nxt = (n0 + 64) < NPIX;

        // issue P reads for PV(n0) first (latency hides under QK MFMAs)
        bf16x8 ap[2][4];
        #pragma unroll
        for (int ks = 0; ks < 2; ks++)
            #pragma unroll
            for (int mg = 0; mg < 4; mg++) {
                const int row = mg * 16 + l16;
                const int bo = (ks * 64 + quad * 16) ^ ((row & 7) << 4);
                ap[ks][mg] = *(const bf16x8*)((const char*)&sps[buf][0] + row * 128 + bo);
            }

        // QK for tile n0+64 -> sps[buf^1] (register-only MFMAs + exp VALU)
        if (nxt) qk_tile(buf ^ 1);

        // PV(n0)
        #pragma unroll
        for (int ks = 0; ks < 2; ks++)
            #pragma unroll
            for (int mg = 0; mg < 4; mg++)
                #pragma unroll
                for (int ct = 0; ct < 4; ct++)
                    acc[mg][ct] = __builtin_amdgcn_mfma_f32_16x16x32_bf16(
                        ap[ks][mg], vf[ct][ks], acc[mg][ct], 0, 0, 0);

        // K prefetch for tile n0+128 (consumed by QK in next body)
        if (n0 + 128 < NPIX) {
            const size_t kb = kbase + (size_t)(n0 + 128) * ND;
            #pragma unroll
            for (int ks = 0; ks < 2; ks++) {
                kfh[ks] = *(const bf16x8*)&kh[kb + ks * 32];
                kfl[ks] = *(const bf16x8*)&kl[kb + ks * 32];
            }
        }
        // V prefetch for PV(n0+64)
        if (nxt) {
            #pragma unroll
            for (int ct = 0; ct < 4; ct++)
                #pragma unroll
                for (int ks = 0; ks < 2; ks++)
                    vf[ct][ks] = *(const bf16x8*)&vb[vbase[ct] + n0 + 64 + ks * 32];
        }

        // non-draining barrier: LDS writes visible; global prefetches in flight
        asm volatile("s_waitcnt lgkmcnt(0)\n\ts_barrier" ::: "memory");
    }

    // rowsum: reduce across quad lanes, then across the 4 nt-waves via LDS
    #pragma unroll
    for (int mg = 0; mg < 4; mg++) {
        lsum[mg] += __shfl_xor(lsum[mg], 16, 64);
        lsum[mg] += __shfl_xor(lsum[mg], 32, 64);
    }
    if (quad == 0) {
        #pragma unroll
        for (int mg = 0; mg < 4; mg++) red[w][mg * 16 + l16] = lsum[mg];
    }
    __syncthreads();
    if (t < 64)
        ivl[t] = 1.f / (red[0][t] + red[1][t] + red[2][t] + red[3][t]);
    __syncthreads();

    // epilogue: out = acc/l + x; D rows m = mg*16+quad*4+r, col c = l16
    #pragma unroll
    for (int mg = 0; mg < 4; mg++) {
        const int mrow = mg * 16 + quad * 4;
        const float4 il4 = *(const float4*)&ivl[mrow];
        const int m = m0 + mrow;
        #pragma unroll
        for (int ct = 0; ct < 4; ct++) {
            const int c = 64 * w + ct * 16 + l16;
            const size_t base = ((size_t)b * NC + c) * NPIX + m;
            const float4 xv = *(const float4*)&x[base];
            const f32x4 a = acc[mg][ct];
            float4 o;
            o.x = fmaf(a[0], il4.x, xv.x);
            o.y = fmaf(a[1], il4.y, xv.y);
            o.z = fmaf(a[2], il4.z, xv.z);
            o.w = fmaf(a[3], il4.w, xv.w);
            *(float4*)&out[base] = o;
        }
    }
}

extern "C" void kernel_launch(void* const* d_in, const int* in_sizes, int n_in,
                              void* d_out, int out_size, void* d_ws, size_t ws_size,
                              hipStream_t stream)
{
    const float* x  = (const float*)d_in[0];
    const float* Wq = (const float*)d_in[1];
    const float* bq = (const float*)d_in[2];
    const float* Wk = (const float*)d_in[3];
    const float* bk = (const float*)d_in[4];
    const float* Wv = (const float*)d_in[5];
    const float* bv = (const float*)d_in[6];
    float* outp = (float*)d_out;

    const size_t XT = (size_t)NB * NPIX * 256;   // 8,388,608
    const size_t QK = (size_t)NB * NPIX * ND;    // 2,097,152
    ushort* xt_h = (ushort*)d_ws;
    ushort* xt_l = xt_h + XT;
    ushort* v_b  = xt_l;              // alias: conv_v (after conv_split) overwrites xt_l
    ushort* q_h  = xt_l + XT;
    ushort* q_l  = q_h + QK;
    ushort* k_h  = q_l + QK;
    ushort* k_l  = k_h + QK;
    ushort* wtq_h = k_l + QK;         // 9*64*256 = 147456 each
    ushort* wtq_l = wtq_h + 147456;
    ushort* wtk_h = wtq_l + 147456;
    ushort* wtk_l = wtk_h + 147456;
    ushort* wtv_h = wtk_l + 147456;   // 9*256*256 = 589824

    dim3 blk(256);
    prep_k<<<dim3(2432), blk, 0, stream>>>(
        x, Wq, Wk, Wv, xt_h, xt_l, wtq_h, wtq_l, wtk_h, wtk_l, wtv_h);
    conv_split_k<<<dim3(16, NB, 2), blk, 65920, stream>>>(
        xt_h, xt_l, wtq_h, wtq_l, wtk_h, wtk_l, bq, bk, q_h, q_l, k_h, k_l);
    conv_v_k<<<dim3(16, NB, 4), blk, 46912, stream>>>(xt_h, wtv_h, bv, v_b);
    attn_k<<<dim3(512), blk, 0, stream>>>(q_h, q_l, k_h, k_l, v_b, x, outp);
}

// Round 10
// 419.605 us; speedup vs baseline: 1.1741x; 1.0041x over previous
//
#include <hip/hip_runtime.h>
#include <math.h>

#define NB   8
#define NC   256
#define ND   64
#define NPIX 4096

typedef short bf16x8 __attribute__((ext_vector_type(8)));   // 8 bf16 (4 VGPRs)
typedef float f32x4  __attribute__((ext_vector_type(4)));
typedef float f32x16 __attribute__((ext_vector_type(16)));

static __device__ __forceinline__ ushort f2bf(float f) {
    uint u = __float_as_uint(f);
    u += 0x7fffu + ((u >> 16) & 1u);      // round-to-nearest-even
    return (ushort)(u >> 16);
}
static __device__ __forceinline__ float bf2f(ushort h) {
    return __uint_as_float(((uint)h) << 16);
}

// ---------------------------------------------------------------------------
// prep_k: transpose_w (ids 0..383) + transpose_x (ids 384..2431) fused (R9-
// proven, +3us). NEW: transpose_x blocks XCD-pinned by batch (b = xid&7) so
// xt_h/xt_l[b] are WRITTEN on XCD b — resident in that XCD's L2 when the
// (also b-pinned) conv blocks read them. Shared LDS 17408 B.
// ---------------------------------------------------------------------------
__global__ __launch_bounds__(256) void prep_k(
    const float* __restrict__ x,
    const float* __restrict__ Wq, const float* __restrict__ Wk,
    const float* __restrict__ Wv,
    ushort* __restrict__ xth, ushort* __restrict__ xtl,
    ushort* __restrict__ qh, ushort* __restrict__ ql,
    ushort* __restrict__ kh, ushort* __restrict__ kl,
    ushort* __restrict__ vh)
{
    __shared__ char shbuf[64 * 68 * 4];
    const int id = blockIdx.x;
    const int t = threadIdx.x;

    if (id < 384) {
        // ---- transpose_w body (g = id) ----
        float* wb = (float*)shbuf;
        const int g = id;
        const float* src;
        ushort *dh, *dl;
        int co, Co, split;
        if (g < 64)       { src = Wq + (size_t)g * 2304; co = g;       Co = 64;  dh = qh; dl = ql; split = 1; }
        else if (g < 128) { src = Wk + (size_t)(g - 64) * 2304; co = g - 64; Co = 64; dh = kh; dl = kl; split = 1; }
        else              { src = Wv + (size_t)(g - 128) * 2304; co = g - 128; Co = 256; dh = vh; dl = nullptr; split = 0; }

        for (int i = t; i < 2304; i += 256) wb[i] = src[i];
        __syncthreads();
        for (int j = t; j < 2304; j += 256) {
            const int rs = j >> 8, ci = j & 255;
            const float v = wb[ci * 9 + rs];
            const ushort hv = f2bf(v);
            const size_t o = ((size_t)(rs * Co + co)) * 256 + ci;
            dh[o] = hv;
            if (split) dl[o] = f2bf(v - bf2f(hv));
        }
    } else {
        // ---- transpose_x body, XCD-pinned: b = xid&7 ----
        float (*tile)[68] = (float(*)[68])shbuf;
        const int xid = id - 384;
        const int b = xid & 7;
        const int p0 = ((xid >> 3) & 63) * 64;
        const int c0 = (xid >> 9) * 64;

        const int cl = t >> 4, p4 = (t & 15) * 4;
        #pragma unroll
        for (int i = 0; i < 4; i++) {
            const int c = cl + 16 * i;
            *(float4*)&tile[c][p4] =
                *(const float4*)&x[((size_t)(b * NC + c0 + c)) * NPIX + p0 + p4];
        }
        __syncthreads();

        const int pl = t & 63, ch = t >> 6;
        float v[16];
        #pragma unroll
        for (int j = 0; j < 16; j++) v[j] = tile[ch * 16 + j][pl];
        ushort h[16], l[16];
        #pragma unroll
        for (int j = 0; j < 16; j++) {
            h[j] = f2bf(v[j]);
            l[j] = f2bf(v[j] - bf2f(h[j]));
        }
        const size_t o = ((size_t)(b * NPIX + p0 + pl)) * 256 + c0 + ch * 16;
        *(uint4*)&xth[o]     = *(uint4*)&h[0];
        *(uint4*)&xth[o + 8] = *(uint4*)&h[8];
        *(uint4*)&xtl[o]     = *(uint4*)&l[0];
        *(uint4*)&xtl[o + 8] = *(uint4*)&l[8];
    }
}

// ---------------------------------------------------------------------------
// MFMA conv (q/k, split-bf16 3-term). R0 structure (proven), XCD-pinned
// grid: 1-D 256, b = id&7 -> all blocks of batch b on XCD b; their shared
// xt slab (4 MB) fits that XCD's 4 MiB L2 (was hq-major: every XCD held all
// 8 batches' slabs = 32 MB -> HBM misses in the per-chunk x-stage).
// dyn LDS 65920 B.
// ---------------------------------------------------------------------------
__global__ __launch_bounds__(256) void conv_split_k(
    const ushort* __restrict__ xth, const ushort* __restrict__ xtl,
    const ushort* __restrict__ wqh, const ushort* __restrict__ wql,
    const ushort* __restrict__ wkh, const ushort* __restrict__ wkl,
    const float* __restrict__ bq, const float* __restrict__ bk,
    ushort* __restrict__ qoh, ushort* __restrict__ qol,
    ushort* __restrict__ koh, ushort* __restrict__ kol)
{
    extern __shared__ char smem[];
    ushort* xsh = (ushort*)smem;                 // [6][66][24]
    ushort* xsl = xsh + 6 * 66 * 24;             // [6][66][24]
    ushort* wsp = xsl + 6 * 66 * 24;             // [9][64][24] (one w-plane at a time)
    float*  sbias = (float*)(wsp + 9 * 64 * 24); // [64]

    const int id = blockIdx.x;
    const int b = id & 7, hq = (id >> 3) & 15, ct = id >> 7;
    const ushort* wth = ct ? wkh : wqh;
    const ushort* wtl = ct ? wkl : wql;
    const float*  bias = ct ? bk : bq;
    ushort* outh = ct ? koh : qoh;
    ushort* outl = ct ? kol : qol;

    const int t = threadIdx.x;
    const int wv = t >> 6, lane = t & 63;
    const int l31 = lane & 31, khl = lane >> 5;
    const int lanebase = l31 * 24 + khl * 8;
    const int h = hq * 4 + wv;

    if (t < 64) sbias[t] = bias[t];
    for (int i = t; i < 384; i += 256) {
        const int p = i / 192, r2 = i % 192;
        const int row = r2 / 32, e = (r2 % 32) / 16, ci = r2 & 15;
        (p ? xsl : xsh)[(row * 66 + e * 65) * 24 + ci] = 0;
    }

    f32x16 a00 = {0}, a01 = {0}, a10 = {0}, a11 = {0};  // [ms(co)][ns(pix)]

    for (int ch = 0; ch < 16; ch++) {
        __syncthreads();
        const int ci0 = ch * 16;
        #pragma unroll
        for (int pl2 = 0; pl2 < 2; pl2++) {
            const ushort* src = pl2 ? xtl : xth;
            ushort* dst = pl2 ? xsl : xsh;
            #pragma unroll
            for (int i = 0; i < 3; i++) {
                const int a = i * 256 + t;
                const int cih = a & 1, col = (a >> 1) & 63, row = a >> 7;
                const int hs = hq * 4 + row - 1;
                uint4 val = {0, 0, 0, 0};
                if (hs >= 0 && hs < 64)
                    val = *(const uint4*)&src[((size_t)(b * NPIX + hs * 64 + col)) * 256 + ci0 + cih * 8];
                *(uint4*)&dst[(row * 66 + 1 + col) * 24 + cih * 8] = val;
            }
        }
        #pragma unroll
        for (int i = 0; i < 5; i++) {
            const int a = i * 256 + t;
            if (a < 1152) {
                const int cih = a & 1, co = (a >> 1) & 63, rs = a >> 7;
                uint4 wv4 = *(const uint4*)&wth[((size_t)(rs * 64 + co)) * 256 + ci0 + cih * 8];
                *(uint4*)&wsp[(rs * 64 + co) * 24 + cih * 8] = wv4;
            }
        }
        __syncthreads();
        // pass0: (wh.xh) + (wh.xl)
        #pragma unroll
        for (int rs = 0; rs < 9; rs++) {
            const int r = rs / 3, s = rs % 3;
            bf16x8 A0 = *(const bf16x8*)&wsp[rs * 1536 + lanebase];
            bf16x8 A1 = *(const bf16x8*)&wsp[rs * 1536 + 768 + lanebase];
            const int xo = ((wv + r) * 66 + s) * 24 + lanebase;
            bf16x8 B0h = *(const bf16x8*)&xsh[xo];
            bf16x8 B1h = *(const bf16x8*)&xsh[xo + 768];
            bf16x8 B0l = *(const bf16x8*)&xsl[xo];
            bf16x8 B1l = *(const bf16x8*)&xsl[xo + 768];
            a00 = __builtin_amdgcn_mfma_f32_32x32x16_bf16(A0, B0h, a00, 0, 0, 0);
            a01 = __builtin_amdgcn_mfma_f32_32x32x16_bf16(A0, B1h, a01, 0, 0, 0);
            a10 = __builtin_amdgcn_mfma_f32_32x32x16_bf16(A1, B0h, a10, 0, 0, 0);
            a11 = __builtin_amdgcn_mfma_f32_32x32x16_bf16(A1, B1h, a11, 0, 0, 0);
            a00 = __builtin_amdgcn_mfma_f32_32x32x16_bf16(A0, B0l, a00, 0, 0, 0);
            a01 = __builtin_amdgcn_mfma_f32_32x32x16_bf16(A0, B1l, a01, 0, 0, 0);
            a10 = __builtin_amdgcn_mfma_f32_32x32x16_bf16(A1, B0l, a10, 0, 0, 0);
            a11 = __builtin_amdgcn_mfma_f32_32x32x16_bf16(A1, B1l, a11, 0, 0, 0);
        }
        __syncthreads();
        #pragma unroll
        for (int i = 0; i < 5; i++) {
            const int a = i * 256 + t;
            if (a < 1152) {
                const int cih = a & 1, co = (a >> 1) & 63, rs = a >> 7;
                uint4 wv4 = *(const uint4*)&wtl[((size_t)(rs * 64 + co)) * 256 + ci0 + cih * 8];
                *(uint4*)&wsp[(rs * 64 + co) * 24 + cih * 8] = wv4;
            }
        }
        __syncthreads();
        // pass1: (wl.xh)
        #pragma unroll
        for (int rs = 0; rs < 9; rs++) {
            const int r = rs / 3, s = rs % 3;
            bf16x8 A0 = *(const bf16x8*)&wsp[rs * 1536 + lanebase];
            bf16x8 A1 = *(const bf16x8*)&wsp[rs * 1536 + 768 + lanebase];
            const int xo = ((wv + r) * 66 + s) * 24 + lanebase;
            bf16x8 B0h = *(const bf16x8*)&xsh[xo];
            bf16x8 B1h = *(const bf16x8*)&xsh[xo + 768];
            a00 = __builtin_amdgcn_mfma_f32_32x32x16_bf16(A0, B0h, a00, 0, 0, 0);
            a01 = __builtin_amdgcn_mfma_f32_32x32x16_bf16(A0, B1h, a01, 0, 0, 0);
            a10 = __builtin_amdgcn_mfma_f32_32x32x16_bf16(A1, B0h, a10, 0, 0, 0);
            a11 = __builtin_amdgcn_mfma_f32_32x32x16_bf16(A1, B1h, a11, 0, 0, 0);
        }
    }

    const float4* sb4 = (const float4*)sbias;
    #pragma unroll
    for (int ms = 0; ms < 2; ms++)
        #pragma unroll
        for (int ns = 0; ns < 2; ns++) {
            const f32x16 av = ms ? (ns ? a11 : a10) : (ns ? a01 : a00);
            const int p = h * 64 + ns * 32 + l31;
            #pragma unroll
            for (int g = 0; g < 4; g++) {
                const float4 bi = sb4[ms * 8 + 2 * g + khl];
                float v0 = av[4 * g + 0] + bi.x;
                float v1 = av[4 * g + 1] + bi.y;
                float v2 = av[4 * g + 2] + bi.z;
                float v3 = av[4 * g + 3] + bi.w;
                ushort4 hv, lv;
                hv.x = f2bf(v0); lv.x = f2bf(v0 - bf2f(hv.x));
                hv.y = f2bf(v1); lv.y = f2bf(v1 - bf2f(hv.y));
                hv.z = f2bf(v2); lv.z = f2bf(v2 - bf2f(hv.z));
                hv.w = f2bf(v3); lv.w = f2bf(v3 - bf2f(hv.w));
                const size_t o = ((size_t)(b * NPIX + p)) * 64 + ms * 32 + 8 * g + 4 * khl;
                *(ushort4*)&outh[o] = hv;
                *(ushort4*)&outl[o] = lv;
            }
        }
}

// ---------------------------------------------------------------------------
// MFMA conv (v, plain bf16). R0 structure, XCD-pinned grid: 1-D 512,
// b = id&7 (same mechanism as conv_split). dyn LDS 46912 B.
// ---------------------------------------------------------------------------
__global__ __launch_bounds__(256) void conv_v_k(
    const ushort* __restrict__ xth, const ushort* __restrict__ wtv,
    const float* __restrict__ bv, ushort* __restrict__ vout)
{
    extern __shared__ char smem[];
    ushort* xsh = (ushort*)smem;                 // [6][66][24]
    ushort* wsp = xsh + 6 * 66 * 24;             // [9][64][24]
    float*  sbias = (float*)(wsp + 9 * 64 * 24); // [64]

    const int id = blockIdx.x;
    const int b = id & 7, hq = (id >> 3) & 15, co0 = (id >> 7) * 64;
    const int t = threadIdx.x;
    const int wv = t >> 6, lane = t & 63;
    const int l31 = lane & 31, khl = lane >> 5;
    const int lanebase = l31 * 24 + khl * 8;
    const int h = hq * 4 + wv;

    if (t < 64) sbias[t] = bv[co0 + t];
    for (int i = t; i < 192; i += 256) {
        const int row = i / 32, e = (i % 32) / 16, ci = i & 15;
        xsh[(row * 66 + e * 65) * 24 + ci] = 0;
    }

    f32x16 a00 = {0}, a01 = {0}, a10 = {0}, a11 = {0};  // [ms(pix)][ns(co)]

    for (int ch = 0; ch < 16; ch++) {
        __syncthreads();
        const int ci0 = ch * 16;
        #pragma unroll
        for (int i = 0; i < 3; i++) {
            const int a = i * 256 + t;
            const int cih = a & 1, col = (a >> 1) & 63, row = a >> 7;
            const int hs = hq * 4 + row - 1;
            uint4 val = {0, 0, 0, 0};
            if (hs >= 0 && hs < 64)
                val = *(const uint4*)&xth[((size_t)(b * NPIX + hs * 64 + col)) * 256 + ci0 + cih * 8];
            *(uint4*)&xsh[(row * 66 + 1 + col) * 24 + cih * 8] = val;
        }
        #pragma unroll
        for (int i = 0; i < 5; i++) {
            const int a = i * 256 + t;
            if (a < 1152) {
                const int cih = a & 1, co = (a >> 1) & 63, rs = a >> 7;
                uint4 wv4 = *(const uint4*)&wtv[((size_t)(rs * 256 + co0 + co)) * 256 + ci0 + cih * 8];
                *(uint4*)&wsp[(rs * 64 + co) * 24 + cih * 8] = wv4;
            }
        }
        __syncthreads();
        #pragma unroll
        for (int rs = 0; rs < 9; rs++) {
            const int r = rs / 3, s = rs % 3;
            const int xo = ((wv + r) * 66 + s) * 24 + lanebase;
            bf16x8 A0 = *(const bf16x8*)&xsh[xo];
            bf16x8 A1 = *(const bf16x8*)&xsh[xo + 768];
            bf16x8 B0 = *(const bf16x8*)&wsp[rs * 1536 + lanebase];
            bf16x8 B1 = *(const bf16x8*)&wsp[rs * 1536 + 768 + lanebase];
            a00 = __builtin_amdgcn_mfma_f32_32x32x16_bf16(A0, B0, a00, 0, 0, 0);
            a01 = __builtin_amdgcn_mfma_f32_32x32x16_bf16(A0, B1, a01, 0, 0, 0);
            a10 = __builtin_amdgcn_mfma_f32_32x32x16_bf16(A1, B0, a10, 0, 0, 0);
            a11 = __builtin_amdgcn_mfma_f32_32x32x16_bf16(A1, B1, a11, 0, 0, 0);
        }
    }

    #pragma unroll
    for (int ns = 0; ns < 2; ns++) {
        const int co = co0 + ns * 32 + l31;
        const float bi = sbias[ns * 32 + l31];
        #pragma unroll
        for (int ms = 0; ms < 2; ms++) {
            const f32x16 av = ms ? (ns ? a11 : a10) : (ns ? a01 : a00);
            #pragma unroll
            for (int g = 0; g < 4; g++) {
                const int p = h * 64 + ms * 32 + 8 * g + 4 * khl;
                ushort4 ov;
                ov.x = f2bf(av[4 * g + 0] + bi);
                ov.y = f2bf(av[4 * g + 1] + bi);
                ov.z = f2bf(av[4 * g + 2] + bi);
                ov.w = f2bf(av[4 * g + 3] + bi);
                *(ushort4*)&vout[((size_t)(b * NC + co)) * NPIX + p] = ov;
            }
        }
    }
}

// ---------------------------------------------------------------------------
// MFMA flash attention v7 (R3/R9, session best): pipeline-skewed, ONE lgkm-
// only barrier per iter, K/V register prefetch, P buffer 128B rows + XOR
// swizzle byte^=(row&7)<<4 both sides. Bit-identical numerics to v4.
// grid 512 1-D (b = id&7 -> XCD pin), block 256, LDS ~17.7 KB.
// ---------------------------------------------------------------------------
__global__ __launch_bounds__(256, 2) void attn_k(
    const ushort* __restrict__ qh, const ushort* __restrict__ ql,
    const ushort* __restrict__ kh, const ushort* __restrict__ kl,
    const ushort* __restrict__ vb, const float* __restrict__ x,
    float* __restrict__ out)
{
    const int id = blockIdx.x;
    const int b  = id & 7;
    const int m0 = (id >> 3) * 64;
    const int t  = threadIdx.x;
    const int w  = t >> 6;
    const int lane = t & 63;
    const int quad = lane >> 4;
    const int l16  = lane & 15;

    __shared__ ushort sps[2][64 * 64];   // P double buffer, 128B rows, swizzled
    __shared__ float  red[4][64];
    __shared__ float  ivl[64];

    // hoisted Q B-frags: B[col=m=l16][k=d]
    bf16x8 aqh[4][2], aql[4][2];
    #pragma unroll
    for (int mg = 0; mg < 4; mg++)
        #pragma unroll
        for (int ks = 0; ks < 2; ks++) {
            const size_t g = ((size_t)b * NPIX + m0 + mg * 16 + l16) * ND + ks * 32 + quad * 8;
            aqh[mg][ks] = *(const bf16x8*)&qh[g];
            aql[mg][ks] = *(const bf16x8*)&ql[g];
        }

    // per-wave base offsets
    const size_t kbase = ((size_t)b * NPIX + 16 * w + l16) * ND + quad * 8;   // + n0*ND + ks*32
    size_t vbase[4];
    #pragma unroll
    for (int ct = 0; ct < 4; ct++)
        vbase[ct] = ((size_t)b * NC + 64 * w + ct * 16 + l16) * NPIX + quad * 8;  // + n0 + ks*32

    // preload K/V frags for n0 = 0
    bf16x8 kfh[2], kfl[2], vf[4][2];
    #pragma unroll
    for (int ks = 0; ks < 2; ks++) {
        kfh[ks] = *(const bf16x8*)&kh[kbase + ks * 32];
        kfl[ks] = *(const bf16x8*)&kl[kbase + ks * 32];
    }
    #pragma unroll
    for (int ct = 0; ct < 4; ct++)
        #pragma unroll
        for (int ks = 0; ks < 2; ks++)
            vf[ct][ks] = *(const bf16x8*)&vb[vbase[ct] + ks * 32];

    f32x4 acc[4][4];
    #pragma unroll
    for (int i = 0; i < 4; i++)
        #pragma unroll
        for (int j = 0; j < 4; j++) acc[i][j] = (f32x4){0.f, 0.f, 0.f, 0.f};
    float lsum[4] = {0.f, 0.f, 0.f, 0.f};

    // QK tile: S^T = K.Q^T (kf regs hold this tile's K), exp, pack -> sps[obuf]
    auto qk_tile = [&](int obuf) {
        #pragma unroll
        for (int mg = 0; mg < 4; mg++) {
            f32x4 s = {0.f, 0.f, 0.f, 0.f};
            #pragma unroll
            for (int ks = 0; ks < 2; ks++) {
                s = __builtin_amdgcn_mfma_f32_16x16x32_bf16(kfh[ks], aqh[mg][ks], s, 0, 0, 0);
                s = __builtin_amdgcn_mfma_f32_16x16x32_bf16(kfl[ks], aqh[mg][ks], s, 0, 0, 0);
                s = __builtin_amdgcn_mfma_f32_16x16x32_bf16(kfh[ks], aql[mg][ks], s, 0, 0, 0);
            }
            const ushort p0 = f2bf(__expf(s[0] - 30.f));
            const ushort p1 = f2bf(__expf(s[1] - 30.f));
            const ushort p2 = f2bf(__expf(s[2] - 30.f));
            const ushort p3 = f2bf(__expf(s[3] - 30.f));
            lsum[mg] += (bf2f(p0) + bf2f(p1)) + (bf2f(p2) + bf2f(p3));
            uint2 pk;
            pk.x = (uint)p0 | ((uint)p1 << 16);
            pk.y = (uint)p2 | ((uint)p3 << 16);
            const int row = mg * 16 + l16;
            const int bo = (32 * w + quad * 8) ^ ((row & 7) << 4);
            *(uint2*)((char*)&sps[obuf][0] + row * 128 + bo) = pk;
        }
    };

    // prologue: QK(0) -> sps[0]; prefetch K(64); barrier
    qk_tile(0);
    {
        const size_t kb = kbase + (size_t)64 * ND;
        #pragma unroll
        for (int ks = 0; ks < 2; ks++) {
            kfh[ks] = *(const bf16x8*)&kh[kb + ks * 32];
            kfl[ks] = *(const bf16x8*)&kl[kb + ks * 32];
        }
    }
    asm volatile("s_waitcnt lgkmcnt(0)\n\ts_barrier" ::: "memory");

    for (int n0 = 0; n0 < NPIX; n0 += 64) {
        const int buf = (n0 >> 6) & 1;
        const bool nxt = (n0 + 64) < NPIX;

        // issue P reads for PV(n0) first (latency hides under QK MFMAs)
        bf16x8 ap[2][4];
        #pragma unroll
        for (int ks = 0; ks < 2; ks++)
            #pragma unroll
            for (int mg = 0; mg < 4; mg++) {
                const int row = mg * 16 + l16;
                const int bo = (ks * 64 + quad * 16) ^ ((row & 7) << 4);
                ap[ks][mg] = *(const bf16x8*)((const char*)&sps[buf][0] + row * 128 + bo);
            }

        // QK for tile n0+64 -> sps[buf^1] (register-only MFMAs + exp VALU)
        if (nxt) qk_tile(buf ^ 1);

        // PV(n0)
        #pragma unroll
        for (int ks = 0; ks < 2; ks++)
            #pragma unroll
            for (int mg = 0; mg < 4; mg++)
                #pragma unroll
                for (int ct = 0; ct < 4; ct++)
                    acc[mg][ct] = __builtin_amdgcn_mfma_f32_16x16x32_bf16(
                        ap[ks][mg], vf[ct][ks], acc[mg][ct], 0, 0, 0);

        // K prefetch for tile n0+128 (consumed by QK in next body)
        if (n0 + 128 < NPIX) {
            const size_t kb = kbase + (size_t)(n0 + 128) * ND;
            #pragma unroll
            for (int ks = 0; ks < 2; ks++) {
                kfh[ks] = *(const bf16x8*)&kh[kb + ks * 32];
                kfl[ks] = *(const bf16x8*)&kl[kb + ks * 32];
            }
        }
        // V prefetch for PV(n0+64)
        if (nxt) {
            #pragma unroll
            for (int ct = 0; ct < 4; ct++)
                #pragma unroll
                for (int ks = 0; ks < 2; ks++)
                    vf[ct][ks] = *(const bf16x8*)&vb[vbase[ct] + n0 + 64 + ks * 32];
        }

        // non-draining barrier: LDS writes visible; global prefetches in flight
        asm volatile("s_waitcnt lgkmcnt(0)\n\ts_barrier" ::: "memory");
    }

    // rowsum: reduce across quad lanes, then across the 4 nt-waves via LDS
    #pragma unroll
    for (int mg = 0; mg < 4; mg++) {
        lsum[mg] += __shfl_xor(lsum[mg], 16, 64);
        lsum[mg] += __shfl_xor(lsum[mg], 32, 64);
    }
    if (quad == 0) {
        #pragma unroll
        for (int mg = 0; mg < 4; mg++) red[w][mg * 16 + l16] = lsum[mg];
    }
    __syncthreads();
    if (t < 64)
        ivl[t] = 1.f / (red[0][t] + red[1][t] + red[2][t] + red[3][t]);
    __syncthreads();

    // epilogue: out = acc/l + x; D rows m = mg*16+quad*4+r, col c = l16
    #pragma unroll
    for (int mg = 0; mg < 4; mg++) {
        const int mrow = mg * 16 + quad * 4;
        const float4 il4 = *(const float4*)&ivl[mrow];
        const int m = m0 + mrow;
        #pragma unroll
        for (int ct = 0; ct < 4; ct++) {
            const int c = 64 * w + ct * 16 + l16;
            const size_t base = ((size_t)b * NC + c) * NPIX + m;
            const float4 xv = *(const float4*)&x[base];
            const f32x4 a = acc[mg][ct];
            float4 o;
            o.x = fmaf(a[0], il4.x, xv.x);
            o.y = fmaf(a[1], il4.y, xv.y);
            o.z = fmaf(a[2], il4.z, xv.z);
            o.w = fmaf(a[3], il4.w, xv.w);
            *(float4*)&out[base] = o;
        }
    }
}

extern "C" void kernel_launch(void* const* d_in, const int* in_sizes, int n_in,
                              void* d_out, int out_size, void* d_ws, size_t ws_size,
                              hipStream_t stream)
{
    const float* x  = (const float*)d_in[0];
    const float* Wq = (const float*)d_in[1];
    const float* bq = (const float*)d_in[2];
    const float* Wk = (const float*)d_in[3];
    const float* bk = (const float*)d_in[4];
    const float* Wv = (const float*)d_in[5];
    const float* bv = (const float*)d_in[6];
    float* outp = (float*)d_out;

    const size_t XT = (size_t)NB * NPIX * 256;   // 8,388,608
    const size_t QK = (size_t)NB * NPIX * ND;    // 2,097,152
    ushort* xt_h = (ushort*)d_ws;
    ushort* xt_l = xt_h + XT;
    ushort* v_b  = xt_l;              // alias: conv_v (after conv_split) overwrites xt_l
    ushort* q_h  = xt_l + XT;
    ushort* q_l  = q_h + QK;
    ushort* k_h  = q_l + QK;
    ushort* k_l  = k_h + QK;
    ushort* wtq_h = k_l + QK;         // 9*64*256 = 147456 each
    ushort* wtq_l = wtq_h + 147456;
    ushort* wtk_h = wtq_l + 147456;
    ushort* wtk_l = wtk_h + 147456;
    ushort* wtv_h = wtk_l + 147456;   // 9*256*256 = 589824

    dim3 blk(256);
    prep_k<<<dim3(2432), blk, 0, stream>>>(
        x, Wq, Wk, Wv, xt_h, xt_l, wtq_h, wtq_l, wtk_h, wtk_l, wtv_h);
    conv_split_k<<<dim3(256), blk, 65920, stream>>>(
        xt_h, xt_l, wtq_h, wtq_l, wtk_h, wtk_l, bq, bk, q_h, q_l, k_h, k_l);
    conv_v_k<<<dim3(512), blk, 46912, stream>>>(xt_h, wtv_h, bv, v_b);
    attn_k<<<dim3(512), blk, 0, stream>>>(q_h, q_l, k_h, k_l, v_b, x, outp);
}